// Round 4
// baseline (35138.687 us; speedup 1.0000x reference)
//
#include <hip/hip_runtime.h>
#include <cstdint>
#include <cstddef>

#define GXd 480
#define GYd 360
#define NBd 2
#define GXY (480*360)
#define NCELL (NBd*GXY)
#define EPSBN 1e-5f

// ---------- order-preserving float <-> uint map (residual atomics only) ----------
__device__ __forceinline__ unsigned mapf(float f){
    unsigned u = __float_as_uint(f);
    return (u & 0x80000000u) ? ~u : (u | 0x80000000u);
}
__device__ __forceinline__ float unmapf(unsigned m){
    return (m & 0x80000000u) ? __uint_as_float(m ^ 0x80000000u)
                             : __uint_as_float(~m);
}

// ---------- bf16 helpers (RTN-even) ----------
__device__ __forceinline__ unsigned short f2bf(float f){
    unsigned u = __float_as_uint(f);
    unsigned r = (u + 0x7FFFu + ((u >> 16) & 1u)) >> 16;
    return (unsigned short)r;
}
__device__ __forceinline__ float bf2f(unsigned short s){
    return __uint_as_float(((unsigned)s) << 16);
}

// ---------- dense layer helper ----------
template<int DIN, int DOUT>
__device__ __forceinline__ void dense(const float (&in)[DIN], float (&out)[DOUT],
                                      const float* __restrict__ w,
                                      const float* __restrict__ b){
#pragma unroll
    for (int j = 0; j < DOUT; j++) out[j] = b[j];
#pragma unroll
    for (int d = 0; d < DIN; d++){
        float v = in[d];
#pragma unroll
        for (int j = 0; j < DOUT; j++) out[j] = fmaf(v, w[d*DOUT + j], out[j]);
    }
}

// ---------- block-level sum/sumsq reduction ----------
template<int D>
__device__ __forceinline__ void reduce_stats(const float (&h)[D], bool valid,
                                             float* __restrict__ gsum,
                                             float* __restrict__ gsq){
    __shared__ float ssum[D];
    __shared__ float ssq[D];
    int tid = threadIdx.x;
    for (int t = tid; t < D; t += 256){ ssum[t] = 0.f; ssq[t] = 0.f; }
    __syncthreads();
#pragma unroll
    for (int j = 0; j < D; j++){
        float v = valid ? h[j] : 0.f;
        float s = v * v;
#pragma unroll
        for (int o = 32; o > 0; o >>= 1){
            v += __shfl_down(v, o, 64);
            s += __shfl_down(s, o, 64);
        }
        if ((tid & 63) == 0){
            atomicAdd(&ssum[j], v);
            atomicAdd(&ssq[j], s);
        }
    }
    __syncthreads();
    for (int t = tid; t < D; t += 256){
        atomicAdd(&gsum[t], ssum[t]);
        atomicAdd(&gsq[t], ssq[t]);
    }
}

// ---------- stats of raw input columns 0..8 ----------
__global__ __launch_bounds__(256)
void k_stats0(const float* __restrict__ fea, float* gsum, float* gsq, int n){
    int i = blockIdx.x*256 + threadIdx.x;
    bool valid = i < n;
    int i2 = valid ? i : 0;
    float x[9];
#pragma unroll
    for (int d = 0; d < 9; d++) x[d] = fea[(size_t)i2*11 + d];
    reduce_stats<9>(x, valid, gsum, gsq);
}

// ---------- finalize BN ----------
__global__ void k_fin(const float* __restrict__ sum, const float* __restrict__ sq,
                      const float* __restrict__ g, const float* __restrict__ bb,
                      float* __restrict__ a_out, float* __restrict__ c_out,
                      int D, float invN){
    int t = threadIdx.x;
    if (t < D){
        float mu  = sum[t] * invN;
        float var = fmaf(-mu, mu, sq[t] * invN);
        float rs  = rsqrtf(var + EPSBN);
        float a   = rs * g[t];
        a_out[t] = a;
        c_out[t] = fmaf(-mu, a, bb[t]);
    }
}

// ---------- layer1: bn0 -> 9x32; z1; stats; voxel count+rank; res atomics ----------
__global__ __launch_bounds__(256)
void k_l1(const float* __restrict__ fea, const int* __restrict__ ind,
          const float* __restrict__ w1, const float* __restrict__ b1,
          const float* __restrict__ a0, const float* __restrict__ c0,
          float* __restrict__ z1, unsigned* __restrict__ pres,
          unsigned* __restrict__ cnt, unsigned* __restrict__ rank,
          float* gsum, float* gsq, int n){
    int i = blockIdx.x*256 + threadIdx.x;
    bool valid = i < n;
    int i2 = valid ? i : 0;
    float x[9];
#pragma unroll
    for (int d = 0; d < 9; d++) x[d] = fmaf(fea[(size_t)i2*11 + d], a0[d], c0[d]);
    float h[32];
    dense<9,32>(x, h, w1, b1);
    if (valid){
        float4* dst = (float4*)(z1 + (size_t)i*32);
#pragma unroll
        for (int q = 0; q < 8; q++)
            dst[q] = make_float4(h[q*4], h[q*4+1], h[q*4+2], h[q*4+3]);
        float r0 = fea[(size_t)i*11 + 9];
        float r1 = fea[(size_t)i*11 + 10];
        int bb = ind[(size_t)i*3 + 0];
        int gx = ind[(size_t)i*3 + 1];
        int gy = ind[(size_t)i*3 + 2];
        unsigned vox = ((unsigned)bb*GXd + (unsigned)gx)*GYd + (unsigned)gy;
        rank[i] = atomicAdd(&cnt[vox], 1u);
        size_t rbase = (size_t)bb*2*GXY + (size_t)gx*GYd + gy;
        atomicMax(pres + rbase,       mapf(r0));
        atomicMax(pres + rbase + GXY, mapf(r1));
    }
    reduce_stats<32>(h, valid, gsum, gsq);
}

// ---------- layer2 ----------
__global__ __launch_bounds__(256)
void k_l2(const float* __restrict__ z1,
          const float* __restrict__ w2, const float* __restrict__ b2,
          const float* __restrict__ a1, const float* __restrict__ c1,
          float* __restrict__ z2, float* gsum, float* gsq, int n){
    __shared__ float4 w2s[32*16];
    for (int e = threadIdx.x; e < 2048; e += 256) ((float*)w2s)[e] = w2[e];
    __syncthreads();
    int i = blockIdx.x*256 + threadIdx.x;
    bool valid = i < n;
    int i2 = valid ? i : 0;
    float h[32];
    const float4* src = (const float4*)(z1 + (size_t)i2*32);
#pragma unroll
    for (int q = 0; q < 8; q++){
        float4 v = src[q];
        h[q*4+0] = fmaxf(fmaf(v.x, a1[q*4+0], c1[q*4+0]), 0.f);
        h[q*4+1] = fmaxf(fmaf(v.y, a1[q*4+1], c1[q*4+1]), 0.f);
        h[q*4+2] = fmaxf(fmaf(v.z, a1[q*4+2], c1[q*4+2]), 0.f);
        h[q*4+3] = fmaxf(fmaf(v.w, a1[q*4+3], c1[q*4+3]), 0.f);
    }
    float acc[64];
#pragma unroll
    for (int j = 0; j < 64; j++) acc[j] = b2[j];
#pragma unroll
    for (int k = 0; k < 32; k++){
        float v = h[k];
#pragma unroll
        for (int q = 0; q < 16; q++){
            float4 w = w2s[k*16 + q];
            acc[q*4+0] = fmaf(v, w.x, acc[q*4+0]);
            acc[q*4+1] = fmaf(v, w.y, acc[q*4+1]);
            acc[q*4+2] = fmaf(v, w.z, acc[q*4+2]);
            acc[q*4+3] = fmaf(v, w.w, acc[q*4+3]);
        }
    }
    if (valid){
        float4* dst = (float4*)(z2 + (size_t)i*64);
#pragma unroll
        for (int q = 0; q < 16; q++)
            dst[q] = make_float4(acc[q*4], acc[q*4+1], acc[q*4+2], acc[q*4+3]);
    }
    reduce_stats<64>(acc, valid, gsum, gsq);
}

// ---------- layer3: z3 bf16; stats from rounded values ----------
__global__ __launch_bounds__(256)
void k_l3(const float* __restrict__ z2,
          const float* __restrict__ w3, const float* __restrict__ b3,
          const float* __restrict__ a2, const float* __restrict__ c2,
          unsigned short* __restrict__ z3, float* gsum, float* gsq, int n){
    __shared__ float4 w3s[64*32];
    for (int e = threadIdx.x; e < 8192; e += 256) ((float*)w3s)[e] = w3[e];
    __syncthreads();
    int i = blockIdx.x*256 + threadIdx.x;
    bool valid = i < n;
    int i2 = valid ? i : 0;
    float h[64];
    const float4* src = (const float4*)(z2 + (size_t)i2*64);
#pragma unroll
    for (int q = 0; q < 16; q++){
        float4 v = src[q];
        h[q*4+0] = fmaxf(fmaf(v.x, a2[q*4+0], c2[q*4+0]), 0.f);
        h[q*4+1] = fmaxf(fmaf(v.y, a2[q*4+1], c2[q*4+1]), 0.f);
        h[q*4+2] = fmaxf(fmaf(v.z, a2[q*4+2], c2[q*4+2]), 0.f);
        h[q*4+3] = fmaxf(fmaf(v.w, a2[q*4+3], c2[q*4+3]), 0.f);
    }
    for (int cb = 0; cb < 128; cb += 32){
        float acc[32];
#pragma unroll
        for (int cc = 0; cc < 32; cc++) acc[cc] = b3[cb + cc];
#pragma unroll
        for (int k = 0; k < 64; k++){
            float v = h[k];
#pragma unroll
            for (int q = 0; q < 8; q++){
                float4 w = w3s[k*32 + (cb >> 2) + q];
                acc[q*4+0] = fmaf(v, w.x, acc[q*4+0]);
                acc[q*4+1] = fmaf(v, w.y, acc[q*4+1]);
                acc[q*4+2] = fmaf(v, w.z, acc[q*4+2]);
                acc[q*4+3] = fmaf(v, w.w, acc[q*4+3]);
            }
        }
        float rv[32];
        unsigned ob[16];
#pragma unroll
        for (int m = 0; m < 16; m++){
            unsigned short lo = f2bf(acc[2*m]);
            unsigned short hi = f2bf(acc[2*m+1]);
            ob[m] = (unsigned)lo | ((unsigned)hi << 16);
            rv[2*m]   = bf2f(lo);
            rv[2*m+1] = bf2f(hi);
        }
        if (valid){
            uint4* dst = (uint4*)(z3 + (size_t)i*128 + cb);
#pragma unroll
            for (int q = 0; q < 4; q++)
                dst[q] = make_uint4(ob[q*4], ob[q*4+1], ob[q*4+2], ob[q*4+3]);
        }
        reduce_stats<32>(rv, valid, gsum + cb, gsq + cb);
    }
}

// ---------- exclusive scan of cnt via block tickets (grid covers NCELL with guard) ----------
__global__ __launch_bounds__(256)
void k_off(const unsigned* __restrict__ cnt, unsigned* __restrict__ off,
           unsigned* __restrict__ gctr){
    __shared__ unsigned wtot[4];
    __shared__ unsigned wbase[4];
    int t = threadIdx.x;
    int lane = t & 63, w = t >> 6;
    int base = blockIdx.x * 1024 + t * 4;
    bool ok = base < NCELL;                 // NCELL % 4 == 0: quad all-in or all-out
    unsigned c0 = 0, c1 = 0, c2 = 0, c3 = 0;
    if (ok){ c0 = cnt[base]; c1 = cnt[base+1]; c2 = cnt[base+2]; c3 = cnt[base+3]; }
    unsigned tot = c0 + c1 + c2 + c3;
    unsigned incl = tot;
#pragma unroll
    for (int o = 1; o < 64; o <<= 1){
        unsigned v = __shfl_up(incl, o, 64);
        if (lane >= o) incl += v;
    }
    if (lane == 63) wtot[w] = incl;
    __syncthreads();
    if (t == 0){
        unsigned bt = wtot[0] + wtot[1] + wtot[2] + wtot[3];
        unsigned gb = atomicAdd(gctr, bt);
        unsigned s = 0;
#pragma unroll
        for (int q = 0; q < 4; q++){ wbase[q] = gb + s; s += wtot[q]; }
    }
    __syncthreads();
    if (ok){
        unsigned tb = wbase[w] + incl - tot;
        off[base]   = tb;
        off[base+1] = tb + c0;
        off[base+2] = tb + c0 + c1;
        off[base+3] = tb + c0 + c1 + c2;
    }
}

// ---------- fill per-cell point lists ----------
__global__ __launch_bounds__(256)
void k_fill(const int* __restrict__ ind, const unsigned* __restrict__ rank,
            const unsigned* __restrict__ off, unsigned* __restrict__ list, int n){
    int i = blockIdx.x*256 + threadIdx.x;
    if (i >= n) return;
    int bb = ind[(size_t)i*3], gx = ind[(size_t)i*3+1], gy = ind[(size_t)i*3+2];
    unsigned vox = ((unsigned)bb*GXd + (unsigned)gx)*GYd + (unsigned)gy;
    list[off[vox] + rank[i]] = (unsigned)i;
}

// ---------- layer4: bn3relu(z3) @ w4-slice (LDS) -> z4 (bf16, per-point rows) ----------
__global__ __launch_bounds__(256)
void k_l4(const unsigned short* __restrict__ z3,
          const float* __restrict__ w4, const float* __restrict__ b4,
          const float* __restrict__ a3, const float* __restrict__ c3,
          unsigned short* __restrict__ z4, int n){
    __shared__ float4 w4s[128*8];            // 128x32 floats = 16 KB
    int c0 = blockIdx.y * 32;
    for (int e = threadIdx.x; e < 4096; e += 256){
        int k = e >> 5, cc = e & 31;
        ((float*)w4s)[e] = w4[k*256 + c0 + cc];
    }
    __syncthreads();
    int t = threadIdx.x;
    int i0 = blockIdx.x*512 + t;
    int i1 = i0 + 256;
    bool v0 = i0 < n, v1 = i1 < n;
    int j0 = v0 ? i0 : 0, j1 = v1 ? i1 : 0;
    float acc0[32], acc1[32];
#pragma unroll
    for (int cc = 0; cc < 32; cc++){ float bv = b4[c0 + cc]; acc0[cc] = bv; acc1[cc] = bv; }
    const uint4* r0p = (const uint4*)(z3 + (size_t)j0*128);
    const uint4* r1p = (const uint4*)(z3 + (size_t)j1*128);
#pragma unroll
    for (int kb = 0; kb < 8; kb++){
        uint4 ua = r0p[kb*2], ub = r0p[kb*2+1];
        uint4 uc = r1p[kb*2], ud = r1p[kb*2+1];
        unsigned u0[8] = {ua.x, ua.y, ua.z, ua.w, ub.x, ub.y, ub.z, ub.w};
        unsigned u1[8] = {uc.x, uc.y, uc.z, uc.w, ud.x, ud.y, ud.z, ud.w};
        float h0[16], h1[16];
#pragma unroll
        for (int m = 0; m < 8; m++){
            int k = kb*16 + 2*m;
            float aL = a3[k], cL = c3[k], aH = a3[k+1], cH = c3[k+1];
            h0[2*m]   = fmaxf(fmaf(__uint_as_float(u0[m] << 16),          aL, cL), 0.f);
            h0[2*m+1] = fmaxf(fmaf(__uint_as_float(u0[m] & 0xFFFF0000u), aH, cH), 0.f);
            h1[2*m]   = fmaxf(fmaf(__uint_as_float(u1[m] << 16),          aL, cL), 0.f);
            h1[2*m+1] = fmaxf(fmaf(__uint_as_float(u1[m] & 0xFFFF0000u), aH, cH), 0.f);
        }
#pragma unroll
        for (int kk = 0; kk < 16; kk++){
            float va = h0[kk], vb = h1[kk];
#pragma unroll
            for (int q = 0; q < 8; q++){
                float4 w = w4s[(kb*16 + kk)*8 + q];
                acc0[q*4+0] = fmaf(va, w.x, acc0[q*4+0]);
                acc0[q*4+1] = fmaf(va, w.y, acc0[q*4+1]);
                acc0[q*4+2] = fmaf(va, w.z, acc0[q*4+2]);
                acc0[q*4+3] = fmaf(va, w.w, acc0[q*4+3]);
                acc1[q*4+0] = fmaf(vb, w.x, acc1[q*4+0]);
                acc1[q*4+1] = fmaf(vb, w.y, acc1[q*4+1]);
                acc1[q*4+2] = fmaf(vb, w.z, acc1[q*4+2]);
                acc1[q*4+3] = fmaf(vb, w.w, acc1[q*4+3]);
            }
        }
    }
    if (v0){
        unsigned ob[16];
#pragma unroll
        for (int m = 0; m < 16; m++)
            ob[m] = (unsigned)f2bf(acc0[2*m]) | ((unsigned)f2bf(acc0[2*m+1]) << 16);
        uint4* d4 = (uint4*)(z4 + (size_t)i0*256 + c0);
#pragma unroll
        for (int q = 0; q < 4; q++)
            d4[q] = make_uint4(ob[q*4], ob[q*4+1], ob[q*4+2], ob[q*4+3]);
    }
    if (v1){
        unsigned ob[16];
#pragma unroll
        for (int m = 0; m < 16; m++)
            ob[m] = (unsigned)f2bf(acc1[2*m]) | ((unsigned)f2bf(acc1[2*m+1]) << 16);
        uint4* d4 = (uint4*)(z4 + (size_t)i1*256 + c0);
#pragma unroll
        for (int q = 0; q < 4; q++)
            d4[q] = make_uint4(ob[q*4], ob[q*4+1], ob[q*4+2], ob[q*4+3]);
    }
}

// ---------- gather-max: one wave per cell, 4 channels per lane ----------
__global__ __launch_bounds__(256)
void k_gather(const unsigned* __restrict__ cnt, const unsigned* __restrict__ off,
              const unsigned* __restrict__ list,
              const unsigned short* __restrict__ z4,
              unsigned short* __restrict__ pooled){
    int lane = threadIdx.x & 63;
    int wid  = blockIdx.x*4 + (threadIdx.x >> 6);
    int wstride = gridDim.x * 4;
    for (int cell = wid; cell < NCELL; cell += wstride){
        unsigned cn = cnt[cell];
        unsigned o  = off[cell];
        float m0 = -__builtin_inff(), m1 = m0, m2 = m0, m3 = m0;
        for (unsigned p = 0; p < cn; p++){
            unsigned pid = list[o + p];
            uint2 u = *(const uint2*)(z4 + (size_t)pid*256 + lane*4);
            m0 = fmaxf(m0, __uint_as_float(u.x << 16));
            m1 = fmaxf(m1, __uint_as_float(u.x & 0xFFFF0000u));
            m2 = fmaxf(m2, __uint_as_float(u.y << 16));
            m3 = fmaxf(m3, __uint_as_float(u.y & 0xFFFF0000u));
        }
        if (cn == 0){ m0 = m1 = m2 = m3 = 0.f; }
        unsigned p0 = (__float_as_uint(m0) >> 16) | (__float_as_uint(m1) & 0xFFFF0000u);
        unsigned p1 = (__float_as_uint(m2) >> 16) | (__float_as_uint(m3) & 0xFFFF0000u);
        *(uint2*)(pooled + (size_t)cell*256 + lane*4) = make_uint2(p0, p1);
    }
}

// ---------- 3x3 maxpool: bf16 channel-last input, planar f32 output ----------
__global__ __launch_bounds__(256)
void k_maxpool(const unsigned short* __restrict__ pooled, float* __restrict__ out){
    int c   = threadIdx.x;
    int gy0 = blockIdx.x * 32;
    int gx0 = blockIdx.y * 4;
    int b   = blockIdx.z;
    const unsigned short* base = pooled + (size_t)b*GXY*256 + c;
    float* obase = out + ((size_t)b*258 + c)*GXY;
    float cmA[4], cmB[4];
#pragma unroll
    for (int g = 0; g < 4; g++){ cmA[g] = 0.f; cmB[g] = 0.f; }
    for (int tt = 0; tt < 34; tt++){
        int yy = gy0 - 1 + tt;
        bool yok = (unsigned)yy < (unsigned)GYd;
        float v[6];
#pragma unroll
        for (int r = 0; r < 6; r++){
            int xx = gx0 - 1 + r;
            float u = -__builtin_inff();
            if (yok && (unsigned)xx < (unsigned)GXd)
                u = bf2f(base[((size_t)xx*GYd + yy)*256]);
            v[r] = u;
        }
        float cm[4];
#pragma unroll
        for (int g = 0; g < 4; g++)
            cm[g] = fmaxf(fmaxf(v[g], v[g+1]), v[g+2]);
        if (tt >= 2){
            int oy = yy - 1;
            if (oy < gy0 + 32 && oy < GYd){
#pragma unroll
                for (int g = 0; g < 4; g++)
                    obase[(size_t)(gx0+g)*GYd + oy] = fmaxf(fmaxf(cmA[g], cmB[g]), cm[g]);
            }
        }
#pragma unroll
        for (int g = 0; g < 4; g++){ cmA[g] = cmB[g]; cmB[g] = cm[g]; }
    }
}

// ---------- residual channels ----------
__global__ __launch_bounds__(256)
void k_res(const unsigned* __restrict__ pres, float* __restrict__ out){
    int idx = blockIdx.x*256 + threadIdx.x;
    const int total = NBd*2*GXY;
    if (idx >= total) return;
    int gy = idx % GYd;
    int t  = idx / GYd;
    int gx = t % GXd;  t /= GXd;
    int r  = t & 1;
    int b  = t >> 1;
    unsigned u = pres[idx];
    float f = u ? unmapf(u) : 0.f;
    out[(((size_t)b*258 + 256 + r)*GXd + gx)*GYd + gy] = f;
}

extern "C" void kernel_launch(void* const* d_in, const int* in_sizes, int n_in,
                              void* d_out, int out_size, void* d_ws, size_t ws_size,
                              hipStream_t stream){
    (void)n_in; (void)out_size; (void)ws_size;
    const float* fea   = (const float*)d_in[0];
    const int*   ind   = (const int*)  d_in[1];
    const float* bn0_g = (const float*)d_in[2];
    const float* bn0_b = (const float*)d_in[3];
    const float* w1    = (const float*)d_in[4];
    const float* b1    = (const float*)d_in[5];
    const float* bn1_g = (const float*)d_in[6];
    const float* bn1_b = (const float*)d_in[7];
    const float* w2    = (const float*)d_in[8];
    const float* b2    = (const float*)d_in[9];
    const float* bn2_g = (const float*)d_in[10];
    const float* bn2_b = (const float*)d_in[11];
    const float* w3    = (const float*)d_in[12];
    const float* b3    = (const float*)d_in[13];
    const float* bn3_g = (const float*)d_in[14];
    const float* bn3_b = (const float*)d_in[15];
    const float* w4    = (const float*)d_in[16];
    const float* b4    = (const float*)d_in[17];

    int n = in_sizes[0] / 11;
    float invN = 1.0f / (float)n;

    // ---- ws layout ----
    const size_t Z4_B     = (size_t)240000*256*2;       // 122,880,000
    const size_t POOL_B   = (size_t)NCELL*256*2;        // 176,947,200
    const size_t PRES_B   = (size_t)NBd*2*GXY*4;        //   5,529,600
    const size_t CNT_B    = (size_t)NCELL*4;            //   2,764,800
    const size_t STAT_B   = 960*4;
    const size_t GCTR_B   = 256;

    char* base = (char*)d_ws;
    unsigned short* z4     = (unsigned short*)base;
    unsigned short* pooled = (unsigned short*)(base + Z4_B);
    // z1/z2/z3 alias the pooled region (dead before k_gather writes it)
    float*          z1     = (float*)(base + Z4_B);
    float*          z2     = (float*)(base + Z4_B + 30720000);
    unsigned short* z3     = (unsigned short*)(base + Z4_B + 92160000);
    unsigned* pres  = (unsigned*)(base + Z4_B + POOL_B);
    unsigned* cnt   = (unsigned*)((char*)pres + PRES_B);
    float*    stats = (float*)((char*)cnt + CNT_B);
    unsigned* gctr  = (unsigned*)((char*)stats + STAT_B);
    unsigned* off   = (unsigned*)((char*)gctr + GCTR_B);
    unsigned* list  = (unsigned*)((char*)off + CNT_B);
    unsigned* rank  = (unsigned*)((char*)list + (size_t)240000*4);

    float* sum0 = stats;       float* sq0 = stats + 16;
    float* sum1 = stats + 32;  float* sq1 = stats + 64;
    float* sum2 = stats + 96;  float* sq2 = stats + 160;
    float* sum3 = stats + 224; float* sq3 = stats + 352;
    float* a0 = stats + 480;   float* c0 = stats + 496;
    float* a1 = stats + 512;   float* c1 = stats + 544;
    float* a2 = stats + 576;   float* c2 = stats + 640;
    float* a3 = stats + 704;   float* c3 = stats + 832;

    // zero pres + cnt + stats + gctr in one shot (contiguous)
    hipMemsetAsync(pres, 0, PRES_B + CNT_B + STAT_B + GCTR_B, stream);

    int nb = (n + 255) / 256;
    k_stats0<<<nb, 256, 0, stream>>>(fea, sum0, sq0, n);
    k_fin<<<1, 128, 0, stream>>>(sum0, sq0, bn0_g, bn0_b, a0, c0, 9,  invN);
    k_l1<<<nb, 256, 0, stream>>>(fea, ind, w1, b1, a0, c0, z1, pres, cnt, rank, sum1, sq1, n);
    k_fin<<<1, 128, 0, stream>>>(sum1, sq1, bn1_g, bn1_b, a1, c1, 32, invN);
    k_l2<<<nb, 256, 0, stream>>>(z1, w2, b2, a1, c1, z2, sum2, sq2, n);
    k_fin<<<1, 128, 0, stream>>>(sum2, sq2, bn2_g, bn2_b, a2, c2, 64, invN);
    k_l3<<<nb, 256, 0, stream>>>(z2, w3, b3, a2, c2, z3, sum3, sq3, n);
    k_fin<<<1, 128, 0, stream>>>(sum3, sq3, bn3_g, bn3_b, a3, c3, 128, invN);

    k_off <<<(NCELL + 1023)/1024, 256, 0, stream>>>(cnt, off, gctr);
    k_fill<<<nb, 256, 0, stream>>>(ind, rank, off, list, n);

    k_l4<<<dim3((n + 511) / 512, 8), 256, 0, stream>>>(z3, w4, b4, a3, c3, z4, n);

    k_gather<<<2048, 256, 0, stream>>>(cnt, off, list, z4, pooled);

    k_maxpool<<<dim3(12, 120, 2), 256, 0, stream>>>(pooled, (float*)d_out);
    k_res<<<(NBd*2*GXY + 255) / 256, 256, 0, stream>>>(pres, (float*)d_out);
}

// Round 5
// 33561.752 us; speedup vs baseline: 1.0470x; 1.0470x over previous
//
#include <hip/hip_runtime.h>
#include <cstdint>
#include <cstddef>

#define GXd 480
#define GYd 360
#define NBd 2
#define GXY (480*360)
#define NCELL (NBd*GXY)
#define EPSBN 1e-5f

// ---------- order-preserving float <-> uint map (residual atomics only) ----------
__device__ __forceinline__ unsigned mapf(float f){
    unsigned u = __float_as_uint(f);
    return (u & 0x80000000u) ? ~u : (u | 0x80000000u);
}
__device__ __forceinline__ float unmapf(unsigned m){
    return (m & 0x80000000u) ? __uint_as_float(m ^ 0x80000000u)
                             : __uint_as_float(~m);
}

// ---------- bf16 helpers (RTN-even) ----------
__device__ __forceinline__ unsigned short f2bf(float f){
    unsigned u = __float_as_uint(f);
    unsigned r = (u + 0x7FFFu + ((u >> 16) & 1u)) >> 16;
    return (unsigned short)r;
}
__device__ __forceinline__ float bf2f(unsigned short s){
    return __uint_as_float(((unsigned)s) << 16);
}

// ---------- dense layer helper ----------
template<int DIN, int DOUT>
__device__ __forceinline__ void dense(const float (&in)[DIN], float (&out)[DOUT],
                                      const float* __restrict__ w,
                                      const float* __restrict__ b){
#pragma unroll
    for (int j = 0; j < DOUT; j++) out[j] = b[j];
#pragma unroll
    for (int d = 0; d < DIN; d++){
        float v = in[d];
#pragma unroll
        for (int j = 0; j < DOUT; j++) out[j] = fmaf(v, w[d*DOUT + j], out[j]);
    }
}

// ---------- block-level sum/sumsq reduction ----------
template<int D>
__device__ __forceinline__ void reduce_stats(const float (&h)[D], bool valid,
                                             float* __restrict__ gsum,
                                             float* __restrict__ gsq){
    __shared__ float ssum[D];
    __shared__ float ssq[D];
    int tid = threadIdx.x;
    for (int t = tid; t < D; t += 256){ ssum[t] = 0.f; ssq[t] = 0.f; }
    __syncthreads();
#pragma unroll
    for (int j = 0; j < D; j++){
        float v = valid ? h[j] : 0.f;
        float s = v * v;
#pragma unroll
        for (int o = 32; o > 0; o >>= 1){
            v += __shfl_down(v, o, 64);
            s += __shfl_down(s, o, 64);
        }
        if ((tid & 63) == 0){
            atomicAdd(&ssum[j], v);
            atomicAdd(&ssq[j], s);
        }
    }
    __syncthreads();
    for (int t = tid; t < D; t += 256){
        atomicAdd(&gsum[t], ssum[t]);
        atomicAdd(&gsq[t], ssq[t]);
    }
}

// ---------- stats of raw input columns 0..8 ----------
__global__ __launch_bounds__(256)
void k_stats0(const float* __restrict__ fea, float* gsum, float* gsq, int n){
    int i = blockIdx.x*256 + threadIdx.x;
    bool valid = i < n;
    int i2 = valid ? i : 0;
    float x[9];
#pragma unroll
    for (int d = 0; d < 9; d++) x[d] = fea[(size_t)i2*11 + d];
    reduce_stats<9>(x, valid, gsum, gsq);
}

// ---------- finalize BN ----------
__global__ void k_fin(const float* __restrict__ sum, const float* __restrict__ sq,
                      const float* __restrict__ g, const float* __restrict__ bb,
                      float* __restrict__ a_out, float* __restrict__ c_out,
                      int D, float invN){
    int t = threadIdx.x;
    if (t < D){
        float mu  = sum[t] * invN;
        float var = fmaf(-mu, mu, sq[t] * invN);
        float rs  = rsqrtf(var + EPSBN);
        float a   = rs * g[t];
        a_out[t] = a;
        c_out[t] = fmaf(-mu, a, bb[t]);
    }
}

// ---------- layer1: bn0 -> 9x32; z1; stats; voxel count+rank; res atomics ----------
__global__ __launch_bounds__(256)
void k_l1(const float* __restrict__ fea, const int* __restrict__ ind,
          const float* __restrict__ w1, const float* __restrict__ b1,
          const float* __restrict__ a0, const float* __restrict__ c0,
          float* __restrict__ z1, unsigned* __restrict__ pres,
          unsigned* __restrict__ cnt, unsigned* __restrict__ rank,
          float* gsum, float* gsq, int n){
    int i = blockIdx.x*256 + threadIdx.x;
    bool valid = i < n;
    int i2 = valid ? i : 0;
    float x[9];
#pragma unroll
    for (int d = 0; d < 9; d++) x[d] = fmaf(fea[(size_t)i2*11 + d], a0[d], c0[d]);
    float h[32];
    dense<9,32>(x, h, w1, b1);
    if (valid){
        float4* dst = (float4*)(z1 + (size_t)i*32);
#pragma unroll
        for (int q = 0; q < 8; q++)
            dst[q] = make_float4(h[q*4], h[q*4+1], h[q*4+2], h[q*4+3]);
        float r0 = fea[(size_t)i*11 + 9];
        float r1 = fea[(size_t)i*11 + 10];
        int bb = ind[(size_t)i*3 + 0];
        int gx = ind[(size_t)i*3 + 1];
        int gy = ind[(size_t)i*3 + 2];
        unsigned vox = ((unsigned)bb*GXd + (unsigned)gx)*GYd + (unsigned)gy;
        rank[i] = atomicAdd(&cnt[vox], 1u);
        size_t rbase = (size_t)bb*2*GXY + (size_t)gx*GYd + gy;
        atomicMax(pres + rbase,       mapf(r0));
        atomicMax(pres + rbase + GXY, mapf(r1));
    }
    reduce_stats<32>(h, valid, gsum, gsq);
}

// ---------- layer2 ----------
__global__ __launch_bounds__(256)
void k_l2(const float* __restrict__ z1,
          const float* __restrict__ w2, const float* __restrict__ b2,
          const float* __restrict__ a1, const float* __restrict__ c1,
          float* __restrict__ z2, float* gsum, float* gsq, int n){
    __shared__ float4 w2s[32*16];
    for (int e = threadIdx.x; e < 2048; e += 256) ((float*)w2s)[e] = w2[e];
    __syncthreads();
    int i = blockIdx.x*256 + threadIdx.x;
    bool valid = i < n;
    int i2 = valid ? i : 0;
    float h[32];
    const float4* src = (const float4*)(z1 + (size_t)i2*32);
#pragma unroll
    for (int q = 0; q < 8; q++){
        float4 v = src[q];
        h[q*4+0] = fmaxf(fmaf(v.x, a1[q*4+0], c1[q*4+0]), 0.f);
        h[q*4+1] = fmaxf(fmaf(v.y, a1[q*4+1], c1[q*4+1]), 0.f);
        h[q*4+2] = fmaxf(fmaf(v.z, a1[q*4+2], c1[q*4+2]), 0.f);
        h[q*4+3] = fmaxf(fmaf(v.w, a1[q*4+3], c1[q*4+3]), 0.f);
    }
    float acc[64];
#pragma unroll
    for (int j = 0; j < 64; j++) acc[j] = b2[j];
#pragma unroll
    for (int k = 0; k < 32; k++){
        float v = h[k];
#pragma unroll
        for (int q = 0; q < 16; q++){
            float4 w = w2s[k*16 + q];
            acc[q*4+0] = fmaf(v, w.x, acc[q*4+0]);
            acc[q*4+1] = fmaf(v, w.y, acc[q*4+1]);
            acc[q*4+2] = fmaf(v, w.z, acc[q*4+2]);
            acc[q*4+3] = fmaf(v, w.w, acc[q*4+3]);
        }
    }
    if (valid){
        float4* dst = (float4*)(z2 + (size_t)i*64);
#pragma unroll
        for (int q = 0; q < 16; q++)
            dst[q] = make_float4(acc[q*4], acc[q*4+1], acc[q*4+2], acc[q*4+3]);
    }
    reduce_stats<64>(acc, valid, gsum, gsq);
}

// ---------- layer3: z3 bf16; stats from rounded values (in-place, no rv[]) ----------
__global__ __launch_bounds__(256)
void k_l3(const float* __restrict__ z2,
          const float* __restrict__ w3, const float* __restrict__ b3,
          const float* __restrict__ a2, const float* __restrict__ c2,
          unsigned short* __restrict__ z3, float* gsum, float* gsq, int n){
    __shared__ float4 w3s[64*32];
    for (int e = threadIdx.x; e < 8192; e += 256) ((float*)w3s)[e] = w3[e];
    __syncthreads();
    int i = blockIdx.x*256 + threadIdx.x;
    bool valid = i < n;
    int i2 = valid ? i : 0;
    float h[64];
    const float4* src = (const float4*)(z2 + (size_t)i2*64);
#pragma unroll
    for (int q = 0; q < 16; q++){
        float4 v = src[q];
        h[q*4+0] = fmaxf(fmaf(v.x, a2[q*4+0], c2[q*4+0]), 0.f);
        h[q*4+1] = fmaxf(fmaf(v.y, a2[q*4+1], c2[q*4+1]), 0.f);
        h[q*4+2] = fmaxf(fmaf(v.z, a2[q*4+2], c2[q*4+2]), 0.f);
        h[q*4+3] = fmaxf(fmaf(v.w, a2[q*4+3], c2[q*4+3]), 0.f);
    }
    for (int cb = 0; cb < 128; cb += 32){
        float acc[32];
#pragma unroll
        for (int cc = 0; cc < 32; cc++) acc[cc] = b3[cb + cc];
#pragma unroll
        for (int k = 0; k < 64; k++){
            float v = h[k];
#pragma unroll
            for (int q = 0; q < 8; q++){
                float4 w = w3s[k*32 + (cb >> 2) + q];
                acc[q*4+0] = fmaf(v, w.x, acc[q*4+0]);
                acc[q*4+1] = fmaf(v, w.y, acc[q*4+1]);
                acc[q*4+2] = fmaf(v, w.z, acc[q*4+2]);
                acc[q*4+3] = fmaf(v, w.w, acc[q*4+3]);
            }
        }
        unsigned ob[16];
#pragma unroll
        for (int m = 0; m < 16; m++){
            unsigned short lo = f2bf(acc[2*m]);
            unsigned short hi = f2bf(acc[2*m+1]);
            ob[m] = (unsigned)lo | ((unsigned)hi << 16);
            acc[2*m]   = bf2f(lo);          // reuse acc for rounded values
            acc[2*m+1] = bf2f(hi);
        }
        if (valid){
            uint4* dst = (uint4*)(z3 + (size_t)i*128 + cb);
#pragma unroll
            for (int q = 0; q < 4; q++)
                dst[q] = make_uint4(ob[q*4], ob[q*4+1], ob[q*4+2], ob[q*4+3]);
        }
        reduce_stats<32>(acc, valid, gsum + cb, gsq + cb);
    }
}

// ---------- exclusive scan of cnt via block tickets (grid covers NCELL with guard) ----------
__global__ __launch_bounds__(256)
void k_off(const unsigned* __restrict__ cnt, unsigned* __restrict__ off,
           unsigned* __restrict__ gctr){
    __shared__ unsigned wtot[4];
    __shared__ unsigned wbase[4];
    int t = threadIdx.x;
    int lane = t & 63, w = t >> 6;
    int base = blockIdx.x * 1024 + t * 4;
    bool ok = base < NCELL;                 // NCELL % 4 == 0: quad all-in or all-out
    unsigned c0 = 0, c1 = 0, c2 = 0, c3 = 0;
    if (ok){ c0 = cnt[base]; c1 = cnt[base+1]; c2 = cnt[base+2]; c3 = cnt[base+3]; }
    unsigned tot = c0 + c1 + c2 + c3;
    unsigned incl = tot;
#pragma unroll
    for (int o = 1; o < 64; o <<= 1){
        unsigned v = __shfl_up(incl, o, 64);
        if (lane >= o) incl += v;
    }
    if (lane == 63) wtot[w] = incl;
    __syncthreads();
    if (t == 0){
        unsigned bt = wtot[0] + wtot[1] + wtot[2] + wtot[3];
        unsigned gb = atomicAdd(gctr, bt);
        unsigned s = 0;
#pragma unroll
        for (int q = 0; q < 4; q++){ wbase[q] = gb + s; s += wtot[q]; }
    }
    __syncthreads();
    if (ok){
        unsigned tb = wbase[w] + incl - tot;
        off[base]   = tb;
        off[base+1] = tb + c0;
        off[base+2] = tb + c0 + c1;
        off[base+3] = tb + c0 + c1 + c2;
    }
}

// ---------- fill per-cell point lists ----------
__global__ __launch_bounds__(256)
void k_fill(const int* __restrict__ ind, const unsigned* __restrict__ rank,
            const unsigned* __restrict__ off, unsigned* __restrict__ list, int n){
    int i = blockIdx.x*256 + threadIdx.x;
    if (i >= n) return;
    int bb = ind[(size_t)i*3], gx = ind[(size_t)i*3+1], gy = ind[(size_t)i*3+2];
    unsigned vox = ((unsigned)bb*GXd + (unsigned)gx)*GYd + (unsigned)gy;
    list[off[vox] + rank[i]] = (unsigned)i;
}

// ---------- layer4: 1 point/thread, cb-loop inside (no spills) ----------
__global__ __launch_bounds__(256)
void k_l4(const unsigned short* __restrict__ z3,
          const float* __restrict__ w4, const float* __restrict__ b4,
          const float* __restrict__ a3, const float* __restrict__ c3,
          unsigned short* __restrict__ z4, int n){
    __shared__ float4 w4s[128*8];            // 16 KB: w4[k][cb*32 .. +32)
    int i = blockIdx.x*256 + threadIdx.x;
    bool valid = i < n;
    int i2 = valid ? i : (n - 1);
    const uint4* rp = (const uint4*)(z3 + (size_t)i2*128);

    for (int cb = 0; cb < 8; cb++){
        // stage this 32-channel weight slice
        for (int e = threadIdx.x; e < 4096; e += 256){
            int k = e >> 5, cc = e & 31;
            ((float*)w4s)[e] = w4[k*256 + cb*32 + cc];
        }
        __syncthreads();

        float acc[32];
#pragma unroll
        for (int cc = 0; cc < 32; cc++) acc[cc] = b4[cb*32 + cc];

#pragma unroll
        for (int kb = 0; kb < 8; kb++){
            uint4 ua = rp[kb*2], ub = rp[kb*2+1];
            unsigned u[8] = {ua.x, ua.y, ua.z, ua.w, ub.x, ub.y, ub.z, ub.w};
            float h[16];
#pragma unroll
            for (int m = 0; m < 8; m++){
                int k = kb*16 + 2*m;
                h[2*m]   = fmaxf(fmaf(__uint_as_float(u[m] << 16),          a3[k],   c3[k]),   0.f);
                h[2*m+1] = fmaxf(fmaf(__uint_as_float(u[m] & 0xFFFF0000u), a3[k+1], c3[k+1]), 0.f);
            }
#pragma unroll
            for (int kk = 0; kk < 16; kk++){
                float v = h[kk];
#pragma unroll
                for (int q = 0; q < 8; q++){
                    float4 w = w4s[(kb*16 + kk)*8 + q];
                    acc[q*4+0] = fmaf(v, w.x, acc[q*4+0]);
                    acc[q*4+1] = fmaf(v, w.y, acc[q*4+1]);
                    acc[q*4+2] = fmaf(v, w.z, acc[q*4+2]);
                    acc[q*4+3] = fmaf(v, w.w, acc[q*4+3]);
                }
            }
        }

        if (valid){
            unsigned ob[16];
#pragma unroll
            for (int m = 0; m < 16; m++)
                ob[m] = (unsigned)f2bf(acc[2*m]) | ((unsigned)f2bf(acc[2*m+1]) << 16);
            uint4* d4 = (uint4*)(z4 + (size_t)i*256 + cb*32);
#pragma unroll
            for (int q = 0; q < 4; q++)
                d4[q] = make_uint4(ob[q*4], ob[q*4+1], ob[q*4+2], ob[q*4+3]);
        }
        __syncthreads();                      // w4s reused next cb
    }
}

// ---------- gather-max: one wave per cell, 4 channels per lane ----------
__global__ __launch_bounds__(256)
void k_gather(const unsigned* __restrict__ cnt, const unsigned* __restrict__ off,
              const unsigned* __restrict__ list,
              const unsigned short* __restrict__ z4,
              unsigned short* __restrict__ pooled){
    int lane = threadIdx.x & 63;
    int wid  = blockIdx.x*4 + (threadIdx.x >> 6);
    int wstride = gridDim.x * 4;
    for (int cell = wid; cell < NCELL; cell += wstride){
        unsigned cn = cnt[cell];
        unsigned o  = off[cell];
        float m0 = -__builtin_inff(), m1 = m0, m2 = m0, m3 = m0;
        for (unsigned p = 0; p < cn; p++){
            unsigned pid = list[o + p];
            uint2 u = *(const uint2*)(z4 + (size_t)pid*256 + lane*4);
            m0 = fmaxf(m0, __uint_as_float(u.x << 16));
            m1 = fmaxf(m1, __uint_as_float(u.x & 0xFFFF0000u));
            m2 = fmaxf(m2, __uint_as_float(u.y << 16));
            m3 = fmaxf(m3, __uint_as_float(u.y & 0xFFFF0000u));
        }
        if (cn == 0){ m0 = m1 = m2 = m3 = 0.f; }
        unsigned p0 = (__float_as_uint(m0) >> 16) | (__float_as_uint(m1) & 0xFFFF0000u);
        unsigned p1 = (__float_as_uint(m2) >> 16) | (__float_as_uint(m3) & 0xFFFF0000u);
        *(uint2*)(pooled + (size_t)cell*256 + lane*4) = make_uint2(p0, p1);
    }
}

// ---------- 3x3 maxpool: bf16 channel-last input, planar f32 output ----------
__global__ __launch_bounds__(256)
void k_maxpool(const unsigned short* __restrict__ pooled, float* __restrict__ out){
    int c   = threadIdx.x;
    int gy0 = blockIdx.x * 32;
    int gx0 = blockIdx.y * 4;
    int b   = blockIdx.z;
    const unsigned short* base = pooled + (size_t)b*GXY*256 + c;
    float* obase = out + ((size_t)b*258 + c)*GXY;
    float cmA[4], cmB[4];
#pragma unroll
    for (int g = 0; g < 4; g++){ cmA[g] = 0.f; cmB[g] = 0.f; }
    for (int tt = 0; tt < 34; tt++){
        int yy = gy0 - 1 + tt;
        bool yok = (unsigned)yy < (unsigned)GYd;
        float v[6];
#pragma unroll
        for (int r = 0; r < 6; r++){
            int xx = gx0 - 1 + r;
            float u = -__builtin_inff();
            if (yok && (unsigned)xx < (unsigned)GXd)
                u = bf2f(base[((size_t)xx*GYd + yy)*256]);
            v[r] = u;
        }
        float cm[4];
#pragma unroll
        for (int g = 0; g < 4; g++)
            cm[g] = fmaxf(fmaxf(v[g], v[g+1]), v[g+2]);
        if (tt >= 2){
            int oy = yy - 1;
            if (oy < gy0 + 32 && oy < GYd){
#pragma unroll
                for (int g = 0; g < 4; g++)
                    obase[(size_t)(gx0+g)*GYd + oy] = fmaxf(fmaxf(cmA[g], cmB[g]), cm[g]);
            }
        }
#pragma unroll
        for (int g = 0; g < 4; g++){ cmA[g] = cmB[g]; cmB[g] = cm[g]; }
    }
}

// ---------- residual channels ----------
__global__ __launch_bounds__(256)
void k_res(const unsigned* __restrict__ pres, float* __restrict__ out){
    int idx = blockIdx.x*256 + threadIdx.x;
    const int total = NBd*2*GXY;
    if (idx >= total) return;
    int gy = idx % GYd;
    int t  = idx / GYd;
    int gx = t % GXd;  t /= GXd;
    int r  = t & 1;
    int b  = t >> 1;
    unsigned u = pres[idx];
    float f = u ? unmapf(u) : 0.f;
    out[(((size_t)b*258 + 256 + r)*GXd + gx)*GYd + gy] = f;
}

extern "C" void kernel_launch(void* const* d_in, const int* in_sizes, int n_in,
                              void* d_out, int out_size, void* d_ws, size_t ws_size,
                              hipStream_t stream){
    (void)n_in; (void)out_size; (void)ws_size;
    const float* fea   = (const float*)d_in[0];
    const int*   ind   = (const int*)  d_in[1];
    const float* bn0_g = (const float*)d_in[2];
    const float* bn0_b = (const float*)d_in[3];
    const float* w1    = (const float*)d_in[4];
    const float* b1    = (const float*)d_in[5];
    const float* bn1_g = (const float*)d_in[6];
    const float* bn1_b = (const float*)d_in[7];
    const float* w2    = (const float*)d_in[8];
    const float* b2    = (const float*)d_in[9];
    const float* bn2_g = (const float*)d_in[10];
    const float* bn2_b = (const float*)d_in[11];
    const float* w3    = (const float*)d_in[12];
    const float* b3    = (const float*)d_in[13];
    const float* bn3_g = (const float*)d_in[14];
    const float* bn3_b = (const float*)d_in[15];
    const float* w4    = (const float*)d_in[16];
    const float* b4    = (const float*)d_in[17];

    int n = in_sizes[0] / 11;
    float invN = 1.0f / (float)n;

    // ---- ws layout ----
    const size_t Z4_B     = (size_t)240000*256*2;       // 122,880,000
    const size_t POOL_B   = (size_t)NCELL*256*2;        // 176,947,200
    const size_t PRES_B   = (size_t)NBd*2*GXY*4;        //   5,529,600
    const size_t CNT_B    = (size_t)NCELL*4;            //   2,764,800
    const size_t STAT_B   = 960*4;
    const size_t GCTR_B   = 256;

    char* base = (char*)d_ws;
    unsigned short* z4     = (unsigned short*)base;
    unsigned short* pooled = (unsigned short*)(base + Z4_B);
    // z1/z2/z3 alias the pooled region (dead before k_gather writes it)
    float*          z1     = (float*)(base + Z4_B);
    float*          z2     = (float*)(base + Z4_B + 30720000);
    unsigned short* z3     = (unsigned short*)(base + Z4_B + 92160000);
    unsigned* pres  = (unsigned*)(base + Z4_B + POOL_B);
    unsigned* cnt   = (unsigned*)((char*)pres + PRES_B);
    float*    stats = (float*)((char*)cnt + CNT_B);
    unsigned* gctr  = (unsigned*)((char*)stats + STAT_B);
    unsigned* off   = (unsigned*)((char*)gctr + GCTR_B);
    unsigned* list  = (unsigned*)((char*)off + CNT_B);
    unsigned* rank  = (unsigned*)((char*)list + (size_t)240000*4);

    float* sum0 = stats;       float* sq0 = stats + 16;
    float* sum1 = stats + 32;  float* sq1 = stats + 64;
    float* sum2 = stats + 96;  float* sq2 = stats + 160;
    float* sum3 = stats + 224; float* sq3 = stats + 352;
    float* a0 = stats + 480;   float* c0 = stats + 496;
    float* a1 = stats + 512;   float* c1 = stats + 544;
    float* a2 = stats + 576;   float* c2 = stats + 640;
    float* a3 = stats + 704;   float* c3 = stats + 832;

    // zero pres + cnt + stats + gctr in one shot (contiguous)
    hipMemsetAsync(pres, 0, PRES_B + CNT_B + STAT_B + GCTR_B, stream);

    int nb = (n + 255) / 256;
    k_stats0<<<nb, 256, 0, stream>>>(fea, sum0, sq0, n);
    k_fin<<<1, 128, 0, stream>>>(sum0, sq0, bn0_g, bn0_b, a0, c0, 9,  invN);
    k_l1<<<nb, 256, 0, stream>>>(fea, ind, w1, b1, a0, c0, z1, pres, cnt, rank, sum1, sq1, n);
    k_fin<<<1, 128, 0, stream>>>(sum1, sq1, bn1_g, bn1_b, a1, c1, 32, invN);
    k_l2<<<nb, 256, 0, stream>>>(z1, w2, b2, a1, c1, z2, sum2, sq2, n);
    k_fin<<<1, 128, 0, stream>>>(sum2, sq2, bn2_g, bn2_b, a2, c2, 64, invN);
    k_l3<<<nb, 256, 0, stream>>>(z2, w3, b3, a2, c2, z3, sum3, sq3, n);
    k_fin<<<1, 128, 0, stream>>>(sum3, sq3, bn3_g, bn3_b, a3, c3, 128, invN);

    k_off <<<(NCELL + 1023)/1024, 256, 0, stream>>>(cnt, off, gctr);
    k_fill<<<nb, 256, 0, stream>>>(ind, rank, off, list, n);

    k_l4<<<nb, 256, 0, stream>>>(z3, w4, b4, a3, c3, z4, n);

    k_gather<<<2048, 256, 0, stream>>>(cnt, off, list, z4, pooled);

    k_maxpool<<<dim3(12, 120, 2), 256, 0, stream>>>(pooled, (float*)d_out);
    k_res<<<(NBd*2*GXY + 255) / 256, 256, 0, stream>>>(pres, (float*)d_out);
}